// Round 5
// baseline (647.956 us; speedup 1.0000x reference)
//
#include <hip/hip_runtime.h>
#include <hip/hip_bf16.h>
#include <hip/hip_cooperative_groups.h>

typedef __bf16 bf16;
typedef __bf16 bf16x8 __attribute__((ext_vector_type(8)));
typedef float floatx4 __attribute__((ext_vector_type(4)));

#define MFMA16(a, b, c) __builtin_amdgcn_mfma_f32_16x16x32_bf16((a), (b), (c), 0, 0, 0)

__device__ inline void gload_lds16(const void* g, void* l) {
    __builtin_amdgcn_global_load_lds((__attribute__((address_space(1))) void*)g,
                                     (__attribute__((address_space(3))) void*)l, 16, 0, 0);
}

#define ST 72  // congruence LDS row stride (bf16 elems)

// ---------------------------------------------------------------------------
// Kernel 1 (fused prep): three roles by blockIdx.x
//   [0,2048)     fold_w2:  W2fT[i*64+l, p] = sum_j W2[p,i*64+j] W[l,j]  (bf16)
//   [2048,2112)  b2f:      b2f[i*64+l]     = sum_j b2[i*64+j]   W[l,j]
//   [2112,3136)  mlp1:     h = silu(Y @ W1 + b1)  via MFMA (K=64), bf16 out
// ---------------------------------------------------------------------------
__global__ __launch_bounds__(256) void prep_fused(
    const float* __restrict__ W2, const float* __restrict__ W,
    const float* __restrict__ b2, const float* __restrict__ Y,
    const float* __restrict__ W1, const float* __restrict__ b1,
    bf16* __restrict__ W2fT, float* __restrict__ b2f, bf16* __restrict__ h)
{
    __shared__ __align__(16) char smem[45056];
    int t = threadIdx.x, bid = blockIdx.x;
    int w = t >> 6, l = t & 63;
    int lm = l & 15, q2 = l >> 4, q8 = q2 * 8;

    if (bid < 2048) {
        int pt = bid & 31, i = bid >> 5;
        bf16* sW = (bf16*)smem;
        bf16* sA = sW + 64 * 72;
        bf16* sT = sA + 128 * 72;
        int p0 = pt * 128;

#pragma unroll
        for (int kk = 0; kk < 16; kk++) {
            int idx = t + 256 * kk;
            sW[(idx >> 6) * 72 + (idx & 63)] = (bf16)W[idx];
        }
        {
            const float* src = W2 + (size_t)p0 * 4096 + i * 64;
#pragma unroll
            for (int kk = 0; kk < 8; kk++) {
                int c = t + 256 * kk;
                int row = c >> 4, j4 = (c & 15) * 4;
                float4 v = *(const float4*)(src + (size_t)row * 4096 + j4);
                bf16 tmp[4] = {(bf16)v.x, (bf16)v.y, (bf16)v.z, (bf16)v.w};
                *(uint2*)(sA + row * 72 + j4) = *(const uint2*)tmp;
            }
        }
        __syncthreads();

        floatx4 acc[2][4] = {};
#pragma unroll
        for (int kc = 0; kc < 2; kc++) {
            bf16x8 a0 = *(const bf16x8*)(sA + (w * 32 + lm) * 72 + kc * 32 + q8);
            bf16x8 a1 = *(const bf16x8*)(sA + (w * 32 + 16 + lm) * 72 + kc * 32 + q8);
#pragma unroll
            for (int jn = 0; jn < 4; jn++) {
                bf16x8 bf_ = *(const bf16x8*)(sW + (jn * 16 + lm) * 72 + kc * 32 + q8);
                acc[0][jn] = MFMA16(a0, bf_, acc[0][jn]);
                acc[1][jn] = MFMA16(a1, bf_, acc[1][jn]);
            }
        }
#pragma unroll
        for (int im = 0; im < 2; im++)
#pragma unroll
            for (int jn = 0; jn < 4; jn++) {
                int pr = w * 32 + im * 16 + q2 * 4;
                int lc = jn * 16 + lm;
                union { bf16 h4[4]; uint2 u; } pk;
#pragma unroll
                for (int r = 0; r < 4; r++) pk.h4[r] = (bf16)acc[im][jn][r];
                *(uint2*)(sT + lc * 136 + pr) = pk.u;
            }
        __syncthreads();
#pragma unroll
        for (int kk = 0; kk < 4; kk++) {
            int c = t + 256 * kk;
            int row = c >> 4, off = (c & 15) * 8;
            uint4 v = *(const uint4*)(sT + row * 136 + off);
            *(uint4*)(W2fT + (size_t)(i * 64 + row) * 4096 + p0 + off) = v;
        }
        return;
    }

    if (bid < 2112) {
        int i = bid - 2048;
        if (t < 64) {
            float acc = 0.f;
            const float* b2r = b2 + i * 64;
            const float* wr_ = W + t * 64;
#pragma unroll
            for (int j = 0; j < 64; j++) acc = fmaf(b2r[j], wr_[j], acc);
            b2f[i * 64 + t] = acc;
        }
        return;
    }

    {
        int q = bid - 2112;
        int m0 = (q >> 5) * 128, n0 = (q & 31) * 128;
        bf16* sY = (bf16*)smem;
        bf16* sWT = sY + 128 * 72;

#pragma unroll
        for (int kk = 0; kk < 8; kk++) {
            int c = t + 256 * kk;
            int row = c >> 4, c4 = (c & 15) * 4;
            float4 v = *(const float4*)(Y + (size_t)(m0 + row) * 64 + c4);
            bf16 tmp[4] = {(bf16)v.x, (bf16)v.y, (bf16)v.z, (bf16)v.w};
            *(uint2*)(sY + row * 72 + c4) = *(const uint2*)tmp;
        }
#pragma unroll
        for (int kk = 0; kk < 8; kk++) {
            int c = t + 256 * kk;
            int k = c >> 5, j4 = (c & 31) * 4;
            float4 v = *(const float4*)(W1 + (size_t)k * 4096 + n0 + j4);
            sWT[(j4 + 0) * 72 + k] = (bf16)v.x;
            sWT[(j4 + 1) * 72 + k] = (bf16)v.y;
            sWT[(j4 + 2) * 72 + k] = (bf16)v.z;
            sWT[(j4 + 3) * 72 + k] = (bf16)v.w;
        }
        __syncthreads();

        int wn = (w & 1) * 64, wm = (w >> 1) * 64;
        floatx4 acc[4][4] = {};
#pragma unroll
        for (int kc = 0; kc < 2; kc++) {
            bf16x8 af[4], bfr[4];
#pragma unroll
            for (int i = 0; i < 4; i++)
                af[i] = *(const bf16x8*)(sWT + (wn + i * 16 + lm) * 72 + kc * 32 + q8);
#pragma unroll
            for (int j = 0; j < 4; j++)
                bfr[j] = *(const bf16x8*)(sY + (wm + j * 16 + lm) * 72 + kc * 32 + q8);
#pragma unroll
            for (int i = 0; i < 4; i++)
#pragma unroll
                for (int j = 0; j < 4; j++)
                    acc[i][j] = MFMA16(af[i], bfr[j], acc[i][j]);
        }
#pragma unroll
        for (int i = 0; i < 4; i++) {
            int nb = n0 + wn + i * 16 + q2 * 4;
            float4 bv = *(const float4*)(b1 + nb);
            float bb[4] = {bv.x, bv.y, bv.z, bv.w};
#pragma unroll
            for (int j = 0; j < 4; j++) {
                int m = m0 + wm + j * 16 + lm;
                union { bf16 h4[4]; uint2 u; } pk;
#pragma unroll
                for (int r = 0; r < 4; r++) {
                    float v = acc[i][j][r] + bb[r];
                    v = v / (1.f + __expf(-v));
                    pk.h4[r] = (bf16)v;
                }
                *(uint2*)(h + (size_t)m * 4096 + nb) = pk.u;
            }
        }
    }
}

// ---------------------------------------------------------------------------
// Merged cooperative kernel: phase 1 = 128x128 GEMM (emb = h.W2f^T + b2f),
// grid.sync(), phase 2 = 4 congruence samples per block (out = F X F^T).
// Grid = 1024 = 4 blocks/CU x 256 CU (co-resident). LDS union 32 KB.
// ---------------------------------------------------------------------------
__global__ __launch_bounds__(256, 4) void gemm_cong(
    const bf16* __restrict__ A, const bf16* __restrict__ BT,
    const float* __restrict__ bias, bf16* __restrict__ C,
    const float* __restrict__ x, float* __restrict__ out)
{
    __shared__ __align__(16) char smem[32768];
    int t = threadIdx.x, w = t >> 6, l = t & 63;
    int bid = blockIdx.x;
    int lm = l & 15, q2 = l >> 4, q8 = q2 * 8;

    // ---- phase 2 sample-0 x prefetch (input-only; hides under grid sync) ----
    int s0 = bid * 4;
    const float4* xb0 = (const float4*)(x + (size_t)s0 * 2304);
    float4 v0 = xb0[t];
    float4 v1 = xb0[t + 256];
    float4 v2 = (t < 64) ? xb0[t + 512] : make_float4(0.f, 0.f, 0.f, 0.f);

    // ================= phase 1: GEMM =================
    {
        bf16* sA = (bf16*)smem;              // [2][4096]
        bf16* sB = (bf16*)(smem + 16384);    // [2][4096]
        int xcd = bid & 7, local = bid >> 3;
        int mt = xcd * 4 + (local & 3), nt = local >> 2;
        int m0 = mt * 128, n0 = nt * 128;
        int soff = ((q2 - (l & 3)) & 3) * 8;
        int wr = (w >> 1) * 64, wc = (w & 1) * 64;
        int rowA = (w * 64 + l) >> 2;
        int ko = (((l & 3) + rowA) & 3) * 8;
        const bf16* pa = A + (size_t)(m0 + rowA) * 4096 + ko;
        const bf16* pb = BT + (size_t)(n0 + rowA) * 4096 + ko;
        const int base0 = (w * 64) * 8, base1 = (w * 64 + 256) * 8;

        floatx4 acc[4][4] = {};

        auto issue = [&](int buf, const bf16* a, const bf16* b) {
            gload_lds16(a, sA + buf * 4096 + base0);
            gload_lds16(a + (size_t)64 * 4096, sA + buf * 4096 + base1);
            gload_lds16(b, sB + buf * 4096 + base0);
            gload_lds16(b + (size_t)64 * 4096, sB + buf * 4096 + base1);
        };

        issue(0, pa, pb);
        pa += 32; pb += 32;
        __syncthreads();

        for (int kt = 0; kt < 128; ++kt) {
            int cur = kt & 1;
            if (kt + 1 < 128) {
                issue(cur ^ 1, pa, pb);
                pa += 32; pb += 32;
            }
            const bf16* LA = sA + cur * 4096;
            const bf16* LB = sB + cur * 4096;
            bf16x8 af[4], bfr[4];
#pragma unroll
            for (int i = 0; i < 4; i++)
                af[i] = *(const bf16x8*)(LA + (wr + i * 16 + lm) * 32 + soff);
#pragma unroll
            for (int j = 0; j < 4; j++)
                bfr[j] = *(const bf16x8*)(LB + (wc + j * 16 + lm) * 32 + soff);
#pragma unroll
            for (int i = 0; i < 4; i++)
#pragma unroll
                for (int j = 0; j < 4; j++)
                    acc[i][j] = MFMA16(af[i], bfr[j], acc[i][j]);
            __syncthreads();
        }

#pragma unroll
        for (int i = 0; i < 4; i++) {
            int r0g = m0 + wr + i * 16 + q2 * 4;
#pragma unroll
            for (int j = 0; j < 4; j++) {
                int cc = n0 + wc + j * 16 + lm;
                float bb = bias[cc];
#pragma unroll
                for (int r = 0; r < 4; r++)
                    C[(size_t)(r0g + r) * 4096 + cc] = (bf16)(acc[i][j][r] + bb);
            }
        }
    }

    __threadfence();
    cooperative_groups::this_grid().sync();

    // ================= phase 2: congruence, 4 samples =================
    {
        bf16* sX = (bf16*)smem;              // 64*72
        bf16* sF = (bf16*)(smem + 9216);
        bf16* sT = (bf16*)(smem + 18432);
        int r0 = (w >> 1) * 32, c0 = (w & 1) * 32;

        const uint4* gf0 = (const uint4*)(C + (size_t)s0 * 4096);
        uint4 f0 = gf0[t], f1 = gf0[t + 256];

        auto mm = [&](const bf16* PA, const bf16* PB, floatx4 acc2[2][2]) {
#pragma unroll
            for (int kc = 0; kc < 2; kc++) {
                bf16x8 a0 = *(const bf16x8*)(PA + (r0 + lm) * ST + kc * 32 + q8);
                bf16x8 a1 = *(const bf16x8*)(PA + (r0 + 16 + lm) * ST + kc * 32 + q8);
                bf16x8 b0 = *(const bf16x8*)(PB + (c0 + lm) * ST + kc * 32 + q8);
                bf16x8 b1 = *(const bf16x8*)(PB + (c0 + 16 + lm) * ST + kc * 32 + q8);
                acc2[0][0] = MFMA16(a0, b0, acc2[0][0]);
                acc2[0][1] = MFMA16(a0, b1, acc2[0][1]);
                acc2[1][0] = MFMA16(a1, b0, acc2[1][0]);
                acc2[1][1] = MFMA16(a1, b1, acc2[1][1]);
            }
        };

        for (int s = 0; s < 4; ++s) {
            // fill sF from regs
            {
                int c = t;
                *(uint4*)(sF + (c >> 3) * ST + (c & 7) * 8) = f0;
                c = t + 256;
                *(uint4*)(sF + (c >> 3) * ST + (c & 7) * 8) = f1;
            }
            // zero X border + padded-diagonal ones
            {
                unsigned* sx32 = (unsigned*)sX;
#pragma unroll
                for (int kk = 0; kk < 4; kk++) {
                    int idx = t + 256 * kk;
                    if (idx < 384) {
                        int r = idx >> 3, d = 24 + (idx & 7);
                        sx32[r * 36 + d] = 0u;
                    } else if (idx < 896) {
                        int k2 = idx - 384;
                        int r = 48 + (k2 >> 5), d = k2 & 31;
                        unsigned val = 0u;
                        if (d == (r >> 1)) val = (r & 1) ? 0x3F800000u : 0x00003F80u;
                        sx32[r * 36 + d] = val;
                    }
                }
            }
            // x fill rows 0-47 cols 0-47
            {
                int c = t;
                bf16 p4[4];
                p4[0] = (bf16)v0.x; p4[1] = (bf16)v0.y; p4[2] = (bf16)v0.z; p4[3] = (bf16)v0.w;
                *(uint2*)(sX + (c / 12) * ST + (c % 12) * 4) = *(const uint2*)p4;
                c = t + 256;
                p4[0] = (bf16)v1.x; p4[1] = (bf16)v1.y; p4[2] = (bf16)v1.z; p4[3] = (bf16)v1.w;
                *(uint2*)(sX + (c / 12) * ST + (c % 12) * 4) = *(const uint2*)p4;
                if (t < 64) {
                    c = t + 512;
                    p4[0] = (bf16)v2.x; p4[1] = (bf16)v2.y; p4[2] = (bf16)v2.z; p4[3] = (bf16)v2.w;
                    *(uint2*)(sX + (c / 12) * ST + (c % 12) * 4) = *(const uint2*)p4;
                }
            }
            __syncthreads();

            // prefetch sample s+1 (overlaps MFMA below)
            if (s < 3) {
                const float4* xb = (const float4*)(x + (size_t)(s0 + s + 1) * 2304);
                v0 = xb[t]; v1 = xb[t + 256];
                if (t < 64) v2 = xb[t + 512];
                const uint4* gf = (const uint4*)(C + (size_t)(s0 + s + 1) * 4096);
                f0 = gf[t]; f1 = gf[t + 256];
            }

            floatx4 z = {0.f, 0.f, 0.f, 0.f};
            {   // S2: Q = X . F^T = T^T; transposed store -> sT = T row-major
                floatx4 a2[2][2] = {{z, z}, {z, z}};
                mm(sX, sF, a2);
#pragma unroll
                for (int i = 0; i < 2; i++)
#pragma unroll
                    for (int j = 0; j < 2; j++) {
                        int R = r0 + i * 16 + q2 * 4;
                        int Cc = c0 + j * 16 + lm;
                        union { bf16 h4[4]; uint2 u; } pk;
#pragma unroll
                        for (int r = 0; r < 4; r++) pk.h4[r] = (bf16)a2[i][j][r];
                        *(uint2*)(sT + Cc * ST + R) = pk.u;
                    }
            }
            __syncthreads();
            {   // S3: out = T . F^T; out symmetric -> float4 store at (Cc, R..R+3)
                floatx4 a3[2][2] = {{z, z}, {z, z}};
                mm(sT, sF, a3);
                float* ob = out + (size_t)(s0 + s) * 4096;
#pragma unroll
                for (int i = 0; i < 2; i++)
#pragma unroll
                    for (int j = 0; j < 2; j++) {
                        int R = r0 + i * 16 + q2 * 4;
                        int Cc = c0 + j * 16 + lm;
                        float4 vout = make_float4(a3[i][j][0], a3[i][j][1],
                                                  a3[i][j][2], a3[i][j][3]);
                        *(float4*)(ob + Cc * 64 + R) = vout;
                    }
            }
            __syncthreads();  // protect sX/sF/sT before next-sample overwrite
        }
    }
}

// ---------------------------------------------------------------------------
// Fallback kernels (used only if cooperative launch is unsupported)
// ---------------------------------------------------------------------------
__global__ __launch_bounds__(256, 4) void gemm_bt_bias(
    const bf16* __restrict__ A, const bf16* __restrict__ BT,
    const float* __restrict__ bias, bf16* __restrict__ C)
{
    __shared__ bf16 sA[2][4096];
    __shared__ bf16 sB[2][4096];
    int t = threadIdx.x, w = t >> 6, l = t & 63;
    int bid = blockIdx.x;
    int xcd = bid & 7, local = bid >> 3;
    int mt = xcd * 4 + (local & 3), nt = local >> 2;
    int m0 = mt * 128, n0 = nt * 128;
    int lm = l & 15, q2 = l >> 4;
    int soff = ((q2 - (l & 3)) & 3) * 8;
    int wr = (w >> 1) * 64, wc = (w & 1) * 64;
    int rowA = (w * 64 + l) >> 2;
    int ko = (((l & 3) + rowA) & 3) * 8;
    const bf16* pa = A + (size_t)(m0 + rowA) * 4096 + ko;
    const bf16* pb = BT + (size_t)(n0 + rowA) * 4096 + ko;
    const int base0 = (w * 64) * 8, base1 = (w * 64 + 256) * 8;

    floatx4 acc[4][4] = {};
    auto issue = [&](int buf, const bf16* a, const bf16* b) {
        gload_lds16(a, &sA[buf][base0]);
        gload_lds16(a + (size_t)64 * 4096, &sA[buf][base1]);
        gload_lds16(b, &sB[buf][base0]);
        gload_lds16(b + (size_t)64 * 4096, &sB[buf][base1]);
    };
    issue(0, pa, pb);
    pa += 32; pb += 32;
    __syncthreads();
    for (int kt = 0; kt < 128; ++kt) {
        int cur = kt & 1;
        if (kt + 1 < 128) { issue(cur ^ 1, pa, pb); pa += 32; pb += 32; }
        const bf16* LA = sA[cur];
        const bf16* LB = sB[cur];
        bf16x8 af[4], bfr[4];
#pragma unroll
        for (int i = 0; i < 4; i++)
            af[i] = *(const bf16x8*)(LA + (wr + i * 16 + lm) * 32 + soff);
#pragma unroll
        for (int j = 0; j < 4; j++)
            bfr[j] = *(const bf16x8*)(LB + (wc + j * 16 + lm) * 32 + soff);
#pragma unroll
        for (int i = 0; i < 4; i++)
#pragma unroll
            for (int j = 0; j < 4; j++)
                acc[i][j] = MFMA16(af[i], bfr[j], acc[i][j]);
        __syncthreads();
    }
#pragma unroll
    for (int i = 0; i < 4; i++) {
        int r0 = m0 + wr + i * 16 + q2 * 4;
#pragma unroll
        for (int j = 0; j < 4; j++) {
            int cc = n0 + wc + j * 16 + lm;
            float bb = bias[cc];
#pragma unroll
            for (int r = 0; r < 4; r++)
                C[(size_t)(r0 + r) * 4096 + cc] = (bf16)(acc[i][j][r] + bb);
        }
    }
}

__global__ __launch_bounds__(256) void batched_congruence(
    const float* __restrict__ x, const bf16* __restrict__ F,
    float* __restrict__ out)
{
    __shared__ bf16 sX[64 * ST], sF[64 * ST], sT[64 * ST];
    int t = threadIdx.x, w = t >> 6, l = t & 63;
    int b = blockIdx.x;
    int lm = l & 15, q2 = l >> 4, q8 = q2 * 8;
    int r0 = (w >> 1) * 32, c0 = (w & 1) * 32;

    const float4* xb = (const float4*)(x + (size_t)b * 2304);
    float4 v0 = xb[t];
    float4 v1 = xb[t + 256];
    float4 v2 = (t < 64) ? xb[t + 512] : make_float4(0.f, 0.f, 0.f, 0.f);
    {
        const uint4* gf = (const uint4*)(F + (size_t)b * 4096);
#pragma unroll
        for (int kk = 0; kk < 2; kk++) {
            int c = t + 256 * kk;
            *(uint4*)(sF + (c >> 3) * ST + (c & 7) * 8) = gf[c];
        }
    }
    {
        unsigned* sx32 = (unsigned*)sX;
#pragma unroll
        for (int kk = 0; kk < 4; kk++) {
            int idx = t + 256 * kk;
            if (idx < 384) {
                int r = idx >> 3, d = 24 + (idx & 7);
                sx32[r * 36 + d] = 0u;
            } else if (idx < 896) {
                int k2 = idx - 384;
                int r = 48 + (k2 >> 5), d = k2 & 31;
                unsigned val = 0u;
                if (d == (r >> 1)) val = (r & 1) ? 0x3F800000u : 0x00003F80u;
                sx32[r * 36 + d] = val;
            }
        }
    }
    {
        int c = t;
        bf16 p4[4];
        p4[0] = (bf16)v0.x; p4[1] = (bf16)v0.y; p4[2] = (bf16)v0.z; p4[3] = (bf16)v0.w;
        *(uint2*)(sX + (c / 12) * ST + (c % 12) * 4) = *(const uint2*)p4;
        c = t + 256;
        p4[0] = (bf16)v1.x; p4[1] = (bf16)v1.y; p4[2] = (bf16)v1.z; p4[3] = (bf16)v1.w;
        *(uint2*)(sX + (c / 12) * ST + (c % 12) * 4) = *(const uint2*)p4;
        if (t < 64) {
            c = t + 512;
            p4[0] = (bf16)v2.x; p4[1] = (bf16)v2.y; p4[2] = (bf16)v2.z; p4[3] = (bf16)v2.w;
            *(uint2*)(sX + (c / 12) * ST + (c % 12) * 4) = *(const uint2*)p4;
        }
    }
    __syncthreads();

    auto mm = [&](const bf16* PA, const bf16* PB, floatx4 acc[2][2]) {
#pragma unroll
        for (int kc = 0; kc < 2; kc++) {
            bf16x8 a0 = *(const bf16x8*)(PA + (r0 + lm) * ST + kc * 32 + q8);
            bf16x8 a1 = *(const bf16x8*)(PA + (r0 + 16 + lm) * ST + kc * 32 + q8);
            bf16x8 b0 = *(const bf16x8*)(PB + (c0 + lm) * ST + kc * 32 + q8);
            bf16x8 b1 = *(const bf16x8*)(PB + (c0 + 16 + lm) * ST + kc * 32 + q8);
            acc[0][0] = MFMA16(a0, b0, acc[0][0]);
            acc[0][1] = MFMA16(a0, b1, acc[0][1]);
            acc[1][0] = MFMA16(a1, b0, acc[1][0]);
            acc[1][1] = MFMA16(a1, b1, acc[1][1]);
        }
    };

    floatx4 z = {0.f, 0.f, 0.f, 0.f};
    {
        floatx4 a2[2][2] = {{z, z}, {z, z}};
        mm(sX, sF, a2);
#pragma unroll
        for (int i = 0; i < 2; i++)
#pragma unroll
            for (int j = 0; j < 2; j++) {
                int R = r0 + i * 16 + q2 * 4;
                int Cc = c0 + j * 16 + lm;
                union { bf16 h4[4]; uint2 u; } pk;
#pragma unroll
                for (int r = 0; r < 4; r++) pk.h4[r] = (bf16)a2[i][j][r];
                *(uint2*)(sT + Cc * ST + R) = pk.u;
            }
    }
    __syncthreads();
    {
        floatx4 a3[2][2] = {{z, z}, {z, z}};
        mm(sT, sF, a3);
        float* ob = out + (size_t)b * 4096;
#pragma unroll
        for (int i = 0; i < 2; i++)
#pragma unroll
            for (int j = 0; j < 2; j++) {
                int R = r0 + i * 16 + q2 * 4;
                int Cc = c0 + j * 16 + lm;
                float4 vout = make_float4(a3[i][j][0], a3[i][j][1], a3[i][j][2], a3[i][j][3]);
                *(float4*)(ob + Cc * 64 + R) = vout;
            }
    }
}

// ---------------------------------------------------------------------------
extern "C" void kernel_launch(void* const* d_in, const int* in_sizes, int n_in,
                              void* d_out, int out_size, void* d_ws, size_t ws_size,
                              hipStream_t stream) {
    const float* x  = (const float*)d_in[0];
    const float* Y  = (const float*)d_in[2];
    const float* W  = (const float*)d_in[3];
    const float* W1 = (const float*)d_in[4];
    const float* b1 = (const float*)d_in[5];
    const float* W2 = (const float*)d_in[6];
    const float* b2 = (const float*)d_in[7];
    float* out = (float*)d_out;

    const size_t NN = (size_t)4096 * 4096;
    bf16* h    = (bf16*)d_ws;
    bf16* W2fT = h + NN;
    bf16* emb  = W2fT + NN;
    float* b2f = (float*)d_out;  // stashed in d_out; consumed by GEMM phase, overwritten by phase 2

    prep_fused<<<3136, 256, 0, stream>>>(W2, W, b2, Y, W1, b1, W2fT, b2f, h);

    const bf16* hA = h; const bf16* bB = W2fT; const float* bb = b2f;
    bf16* cC = emb; const float* xx = x; float* oo = out;
    void* cargs[6] = {(void*)&hA, (void*)&bB, (void*)&bb, (void*)&cC, (void*)&xx, (void*)&oo};
    hipError_t err = hipLaunchCooperativeKernel((const void*)gemm_cong,
                                                dim3(1024), dim3(256), cargs, 0, stream);
    if (err != hipSuccess) {
        // deterministic fallback: same work as two ordered kernels
        gemm_bt_bias<<<1024, 256, 0, stream>>>(h, W2fT, b2f, emb);
        batched_congruence<<<4096, 256, 0, stream>>>(x, emb, out);
    }
}

// Round 6
// 358.236 us; speedup vs baseline: 1.8087x; 1.8087x over previous
//
#include <hip/hip_runtime.h>
#include <hip/hip_bf16.h>

typedef __bf16 bf16;
typedef __bf16 bf16x8 __attribute__((ext_vector_type(8)));
typedef float floatx4 __attribute__((ext_vector_type(4)));
typedef float floatx16 __attribute__((ext_vector_type(16)));

#define MFMA16(a, b, c) __builtin_amdgcn_mfma_f32_16x16x32_bf16((a), (b), (c), 0, 0, 0)
#define MFMA32(a, b, c) __builtin_amdgcn_mfma_f32_32x32x16_bf16((a), (b), (c), 0, 0, 0)

__device__ inline void gload_lds16(const void* g, void* l) {
    __builtin_amdgcn_global_load_lds((__attribute__((address_space(1))) void*)g,
                                     (__attribute__((address_space(3))) void*)l, 16, 0, 0);
}

#define ST 72  // congruence LDS row stride (bf16 elems)

// ---------------------------------------------------------------------------
// Kernel 1 (fused prep): three roles by blockIdx.x
//   [0,2048)     fold_w2:  W2fT[i*64+l, p] = sum_j W2[p,i*64+j] W[l,j]  (bf16)
//   [2048,2112)  b2f:      b2f[i*64+l]     = sum_j b2[i*64+j]   W[l,j]
//   [2112,3136)  mlp1:     h = silu(Y @ W1 + b1)  via MFMA (K=64), bf16 out
// (unchanged from R4 — prep+cong measured ~20 us beyond fixed harness overhead)
// ---------------------------------------------------------------------------
__global__ __launch_bounds__(256) void prep_fused(
    const float* __restrict__ W2, const float* __restrict__ W,
    const float* __restrict__ b2, const float* __restrict__ Y,
    const float* __restrict__ W1, const float* __restrict__ b1,
    bf16* __restrict__ W2fT, float* __restrict__ b2f, bf16* __restrict__ h)
{
    __shared__ __align__(16) char smem[45056];
    int t = threadIdx.x, bid = blockIdx.x;
    int w = t >> 6, l = t & 63;
    int lm = l & 15, q2 = l >> 4, q8 = q2 * 8;

    if (bid < 2048) {
        int pt = bid & 31, i = bid >> 5;
        bf16* sW = (bf16*)smem;
        bf16* sA = sW + 64 * 72;
        bf16* sT = sA + 128 * 72;
        int p0 = pt * 128;

#pragma unroll
        for (int kk = 0; kk < 16; kk++) {
            int idx = t + 256 * kk;
            sW[(idx >> 6) * 72 + (idx & 63)] = (bf16)W[idx];
        }
        {
            const float* src = W2 + (size_t)p0 * 4096 + i * 64;
#pragma unroll
            for (int kk = 0; kk < 8; kk++) {
                int c = t + 256 * kk;
                int row = c >> 4, j4 = (c & 15) * 4;
                float4 v = *(const float4*)(src + (size_t)row * 4096 + j4);
                bf16 tmp[4] = {(bf16)v.x, (bf16)v.y, (bf16)v.z, (bf16)v.w};
                *(uint2*)(sA + row * 72 + j4) = *(const uint2*)tmp;
            }
        }
        __syncthreads();

        floatx4 acc[2][4] = {};
#pragma unroll
        for (int kc = 0; kc < 2; kc++) {
            bf16x8 a0 = *(const bf16x8*)(sA + (w * 32 + lm) * 72 + kc * 32 + q8);
            bf16x8 a1 = *(const bf16x8*)(sA + (w * 32 + 16 + lm) * 72 + kc * 32 + q8);
#pragma unroll
            for (int jn = 0; jn < 4; jn++) {
                bf16x8 bf_ = *(const bf16x8*)(sW + (jn * 16 + lm) * 72 + kc * 32 + q8);
                acc[0][jn] = MFMA16(a0, bf_, acc[0][jn]);
                acc[1][jn] = MFMA16(a1, bf_, acc[1][jn]);
            }
        }
#pragma unroll
        for (int im = 0; im < 2; im++)
#pragma unroll
            for (int jn = 0; jn < 4; jn++) {
                int pr = w * 32 + im * 16 + q2 * 4;
                int lc = jn * 16 + lm;
                union { bf16 h4[4]; uint2 u; } pk;
#pragma unroll
                for (int r = 0; r < 4; r++) pk.h4[r] = (bf16)acc[im][jn][r];
                *(uint2*)(sT + lc * 136 + pr) = pk.u;
            }
        __syncthreads();
#pragma unroll
        for (int kk = 0; kk < 4; kk++) {
            int c = t + 256 * kk;
            int row = c >> 4, off = (c & 15) * 8;
            uint4 v = *(const uint4*)(sT + row * 136 + off);
            *(uint4*)(W2fT + (size_t)(i * 64 + row) * 4096 + p0 + off) = v;
        }
        return;
    }

    if (bid < 2112) {
        int i = bid - 2048;
        if (t < 64) {
            float acc = 0.f;
            const float* b2r = b2 + i * 64;
            const float* wr_ = W + t * 64;
#pragma unroll
            for (int j = 0; j < 64; j++) acc = fmaf(b2r[j], wr_[j], acc);
            b2f[i * 64 + t] = acc;
        }
        return;
    }

    {
        int q = bid - 2112;
        int m0 = (q >> 5) * 128, n0 = (q & 31) * 128;
        bf16* sY = (bf16*)smem;
        bf16* sWT = sY + 128 * 72;

#pragma unroll
        for (int kk = 0; kk < 8; kk++) {
            int c = t + 256 * kk;
            int row = c >> 4, c4 = (c & 15) * 4;
            float4 v = *(const float4*)(Y + (size_t)(m0 + row) * 64 + c4);
            bf16 tmp[4] = {(bf16)v.x, (bf16)v.y, (bf16)v.z, (bf16)v.w};
            *(uint2*)(sY + row * 72 + c4) = *(const uint2*)tmp;
        }
#pragma unroll
        for (int kk = 0; kk < 8; kk++) {
            int c = t + 256 * kk;
            int k = c >> 5, j4 = (c & 31) * 4;
            float4 v = *(const float4*)(W1 + (size_t)k * 4096 + n0 + j4);
            sWT[(j4 + 0) * 72 + k] = (bf16)v.x;
            sWT[(j4 + 1) * 72 + k] = (bf16)v.y;
            sWT[(j4 + 2) * 72 + k] = (bf16)v.z;
            sWT[(j4 + 3) * 72 + k] = (bf16)v.w;
        }
        __syncthreads();

        int wn = (w & 1) * 64, wm = (w >> 1) * 64;
        floatx4 acc[4][4] = {};
#pragma unroll
        for (int kc = 0; kc < 2; kc++) {
            bf16x8 af[4], bfr[4];
#pragma unroll
            for (int i = 0; i < 4; i++)
                af[i] = *(const bf16x8*)(sWT + (wn + i * 16 + lm) * 72 + kc * 32 + q8);
#pragma unroll
            for (int j = 0; j < 4; j++)
                bfr[j] = *(const bf16x8*)(sY + (wm + j * 16 + lm) * 72 + kc * 32 + q8);
#pragma unroll
            for (int i = 0; i < 4; i++)
#pragma unroll
                for (int j = 0; j < 4; j++)
                    acc[i][j] = MFMA16(af[i], bfr[j], acc[i][j]);
        }
#pragma unroll
        for (int i = 0; i < 4; i++) {
            int nb = n0 + wn + i * 16 + q2 * 4;
            float4 bv = *(const float4*)(b1 + nb);
            float bb[4] = {bv.x, bv.y, bv.z, bv.w};
#pragma unroll
            for (int j = 0; j < 4; j++) {
                int m = m0 + wm + j * 16 + lm;
                union { bf16 h4[4]; uint2 u; } pk;
#pragma unroll
                for (int r = 0; r < 4; r++) {
                    float v = acc[i][j][r] + bb[r];
                    v = v / (1.f + __expf(-v));
                    pk.h4[r] = (bf16)v;
                }
                *(uint2*)(h + (size_t)m * 4096 + nb) = pk.u;
            }
        }
    }
}

// ---------------------------------------------------------------------------
// Kernel 2: C = A @ BT^T + bias, 128x128 tile, BK=32, double-buffered LDS,
// one barrier per K-iter. EXPERIMENT: 32x32x16 MFMA (2x2 per wave, 8 MFMA
// per K-tile vs 16 with 16x16x32; measured ceiling 2495 vs 2176 TF).
// A-frag: row = wr+i*32+(l&31), k = (l>>5)*8 + kstep*16. C/D: col = l&31,
// row = (reg&3) + 8*(reg>>2) + 4*(l>>5).
// ---------------------------------------------------------------------------
__global__ __launch_bounds__(256, 4) void gemm_bt_bias(
    const bf16* __restrict__ A, const bf16* __restrict__ BT,
    const float* __restrict__ bias, bf16* __restrict__ C)
{
    __shared__ bf16 sA[2][4096];
    __shared__ bf16 sB[2][4096];
    int t = threadIdx.x, w = t >> 6, l = t & 63;
    int bid = blockIdx.x;
    int xcd = bid & 7, local = bid >> 3;
    int mt = xcd * 4 + (local & 3), nt = local >> 2;
    int m0 = mt * 128, n0 = nt * 128;

    int l31 = l & 31, h1 = l >> 5;
    int wr = (w >> 1) * 64, wc = (w & 1) * 64;
    int fo = h1 * 8;  // frag k-offset within 16-k step

    // staging: chunk c = w*64 + it*256 + l; row = c>>2, ko = (l&3)*8
    int rowA = (w * 64 + l) >> 2, ko = (l & 3) * 8;
    const bf16* pa = A + (size_t)(m0 + rowA) * 4096 + ko;
    const bf16* pb = BT + (size_t)(n0 + rowA) * 4096 + ko;
    const int base0 = (w * 64) * 8, base1 = (w * 64 + 256) * 8;

    floatx16 acc[2][2] = {};

    auto issue = [&](int buf, const bf16* a, const bf16* b) {
        gload_lds16(a, &sA[buf][base0]);
        gload_lds16(a + (size_t)64 * 4096, &sA[buf][base1]);
        gload_lds16(b, &sB[buf][base0]);
        gload_lds16(b + (size_t)64 * 4096, &sB[buf][base1]);
    };

    issue(0, pa, pb);
    pa += 32; pb += 32;
    __syncthreads();

    for (int kt = 0; kt < 128; ++kt) {
        int cur = kt & 1;
        if (kt + 1 < 128) {
            issue(cur ^ 1, pa, pb);
            pa += 32; pb += 32;
        }
        const bf16* LA = sA[cur];
        const bf16* LB = sB[cur];
        bf16x8 a0[2], a1[2], b0[2], b1[2];
#pragma unroll
        for (int i = 0; i < 2; i++) {
            a0[i] = *(const bf16x8*)(LA + (wr + i * 32 + l31) * 32 + fo);
            a1[i] = *(const bf16x8*)(LA + (wr + i * 32 + l31) * 32 + fo + 16);
            b0[i] = *(const bf16x8*)(LB + (wc + i * 32 + l31) * 32 + fo);
            b1[i] = *(const bf16x8*)(LB + (wc + i * 32 + l31) * 32 + fo + 16);
        }
#pragma unroll
        for (int i = 0; i < 2; i++)
#pragma unroll
            for (int j = 0; j < 2; j++) {
                acc[i][j] = MFMA32(a0[i], b0[j], acc[i][j]);
                acc[i][j] = MFMA32(a1[i], b1[j], acc[i][j]);
            }
        __syncthreads();
    }

    // epilogue: row = (reg&3) + 8*(reg>>2) + 4*h1, col = l31
#pragma unroll
    for (int j = 0; j < 2; j++) {
        int cc = n0 + wc + j * 32 + l31;
        float bb = bias[cc];
#pragma unroll
        for (int i = 0; i < 2; i++) {
            int rbase = m0 + wr + i * 32 + 4 * h1;
#pragma unroll
            for (int g = 0; g < 4; g++)
#pragma unroll
                for (int r2 = 0; r2 < 4; r2++)
                    C[(size_t)(rbase + 8 * g + r2) * 4096 + cc] =
                        (bf16)(acc[i][j][4 * g + r2] + bb);
        }
    }
}

// ---------------------------------------------------------------------------
// Kernel 3: out = F X F^T (X symmetric; F = reshape(h W2f + b2f)).
// (unchanged from R4)
// ---------------------------------------------------------------------------
__global__ __launch_bounds__(256) void batched_congruence(
    const float* __restrict__ x, const bf16* __restrict__ F,
    float* __restrict__ out)
{
    __shared__ bf16 sX[64 * ST], sF[64 * ST], sT[64 * ST];
    int t = threadIdx.x, w = t >> 6, l = t & 63;
    int b = blockIdx.x;
    int lm = l & 15, q2 = l >> 4, q8 = q2 * 8;
    int r0 = (w >> 1) * 32, c0 = (w & 1) * 32;

    const float4* xb = (const float4*)(x + (size_t)b * 2304);
    float4 v0 = xb[t];
    float4 v1 = xb[t + 256];
    float4 v2 = (t < 64) ? xb[t + 512] : make_float4(0.f, 0.f, 0.f, 0.f);
    {
        const uint4* gf = (const uint4*)(F + (size_t)b * 4096);
#pragma unroll
        for (int kk = 0; kk < 2; kk++) {
            int c = t + 256 * kk;
            *(uint4*)(sF + (c >> 3) * ST + (c & 7) * 8) = gf[c];
        }
    }
    {
        unsigned* sx32 = (unsigned*)sX;
#pragma unroll
        for (int kk = 0; kk < 4; kk++) {
            int idx = t + 256 * kk;
            if (idx < 384) {
                int r = idx >> 3, d = 24 + (idx & 7);
                sx32[r * 36 + d] = 0u;
            } else if (idx < 896) {
                int k2 = idx - 384;
                int r = 48 + (k2 >> 5), d = k2 & 31;
                unsigned val = 0u;
                if (d == (r >> 1)) val = (r & 1) ? 0x3F800000u : 0x00003F80u;
                sx32[r * 36 + d] = val;
            }
        }
    }
    {
        int c = t;
        bf16 p4[4];
        p4[0] = (bf16)v0.x; p4[1] = (bf16)v0.y; p4[2] = (bf16)v0.z; p4[3] = (bf16)v0.w;
        *(uint2*)(sX + (c / 12) * ST + (c % 12) * 4) = *(const uint2*)p4;
        c = t + 256;
        p4[0] = (bf16)v1.x; p4[1] = (bf16)v1.y; p4[2] = (bf16)v1.z; p4[3] = (bf16)v1.w;
        *(uint2*)(sX + (c / 12) * ST + (c % 12) * 4) = *(const uint2*)p4;
        if (t < 64) {
            c = t + 512;
            p4[0] = (bf16)v2.x; p4[1] = (bf16)v2.y; p4[2] = (bf16)v2.z; p4[3] = (bf16)v2.w;
            *(uint2*)(sX + (c / 12) * ST + (c % 12) * 4) = *(const uint2*)p4;
        }
    }
    __syncthreads();

    auto mm = [&](const bf16* PA, const bf16* PB, floatx4 acc[2][2]) {
#pragma unroll
        for (int kc = 0; kc < 2; kc++) {
            bf16x8 a0 = *(const bf16x8*)(PA + (r0 + lm) * ST + kc * 32 + q8);
            bf16x8 a1 = *(const bf16x8*)(PA + (r0 + 16 + lm) * ST + kc * 32 + q8);
            bf16x8 b0 = *(const bf16x8*)(PB + (c0 + lm) * ST + kc * 32 + q8);
            bf16x8 b1 = *(const bf16x8*)(PB + (c0 + 16 + lm) * ST + kc * 32 + q8);
            acc[0][0] = MFMA16(a0, b0, acc[0][0]);
            acc[0][1] = MFMA16(a0, b1, acc[0][1]);
            acc[1][0] = MFMA16(a1, b0, acc[1][0]);
            acc[1][1] = MFMA16(a1, b1, acc[1][1]);
        }
    };

    floatx4 z = {0.f, 0.f, 0.f, 0.f};
    {   // S2: Q = X . F^T = T^T; transposed store -> sT = T row-major
        floatx4 a2[2][2] = {{z, z}, {z, z}};
        mm(sX, sF, a2);
#pragma unroll
        for (int i = 0; i < 2; i++)
#pragma unroll
            for (int j = 0; j < 2; j++) {
                int R = r0 + i * 16 + q2 * 4;
                int Cc = c0 + j * 16 + lm;
                union { bf16 h4[4]; uint2 u; } pk;
#pragma unroll
                for (int r = 0; r < 4; r++) pk.h4[r] = (bf16)a2[i][j][r];
                *(uint2*)(sT + Cc * ST + R) = pk.u;
            }
    }
    __syncthreads();
    {   // S3: out = T . F^T; out symmetric -> float4 store at (Cc, R..R+3)
        floatx4 a3[2][2] = {{z, z}, {z, z}};
        mm(sT, sF, a3);
        float* ob = out + (size_t)b * 4096;
#pragma unroll
        for (int i = 0; i < 2; i++)
#pragma unroll
            for (int j = 0; j < 2; j++) {
                int R = r0 + i * 16 + q2 * 4;
                int Cc = c0 + j * 16 + lm;
                float4 vout = make_float4(a3[i][j][0], a3[i][j][1], a3[i][j][2], a3[i][j][3]);
                *(float4*)(ob + Cc * 64 + R) = vout;
            }
    }
}

// ---------------------------------------------------------------------------
extern "C" void kernel_launch(void* const* d_in, const int* in_sizes, int n_in,
                              void* d_out, int out_size, void* d_ws, size_t ws_size,
                              hipStream_t stream) {
    const float* x  = (const float*)d_in[0];
    const float* Y  = (const float*)d_in[2];
    const float* W  = (const float*)d_in[3];
    const float* W1 = (const float*)d_in[4];
    const float* b1 = (const float*)d_in[5];
    const float* W2 = (const float*)d_in[6];
    const float* b2 = (const float*)d_in[7];
    float* out = (float*)d_out;

    const size_t NN = (size_t)4096 * 4096;
    bf16* h    = (bf16*)d_ws;
    bf16* W2fT = h + NN;
    bf16* emb  = W2fT + NN;
    float* b2f = (float*)d_out;  // stashed in d_out; read by GEMM, overwritten by cong

    prep_fused<<<3136, 256, 0, stream>>>(W2, W, b2, Y, W1, b1, W2fT, b2f, h);
    gemm_bt_bias<<<1024, 256, 0, stream>>>(h, W2fT, b2f, emb);
    batched_congruence<<<4096, 256, 0, stream>>>(x, emb, out);
}

// Round 7
// 335.452 us; speedup vs baseline: 1.9316x; 1.0679x over previous
//
#include <hip/hip_runtime.h>
#include <hip/hip_bf16.h>

typedef __bf16 bf16;
typedef __bf16 bf16x8 __attribute__((ext_vector_type(8)));
typedef float floatx4 __attribute__((ext_vector_type(4)));

#define MFMA16(a, b, c) __builtin_amdgcn_mfma_f32_16x16x32_bf16((a), (b), (c), 0, 0, 0)

__device__ inline void gload_lds16(const void* g, void* l) {
    __builtin_amdgcn_global_load_lds((__attribute__((address_space(1))) void*)g,
                                     (__attribute__((address_space(3))) void*)l, 16, 0, 0);
}

#define ST 72  // congruence LDS row stride (bf16 elems)

// ---------------------------------------------------------------------------
// Kernel 1 (fused prep): three roles by blockIdx.x
//   [0,2048)     fold_w2:  W2fT[i*64+l, p] = sum_j W2[p,i*64+j] W[l,j]  (bf16)
//                i = bid&63 (FAST), pt = bid>>6: 64-block cohorts cover a
//                contiguous 2 MB row-slab of W2 (full 16 KB rows) for DRAM locality.
//   [2048,2112)  b2f:      b2f[i*64+l]     = sum_j b2[i*64+j]   W[l,j]
//   [2112,3136)  mlp1:     h = silu(Y @ W1 + b1)  via MFMA (K=64), bf16 out
// ---------------------------------------------------------------------------
__global__ __launch_bounds__(256) void prep_fused(
    const float* __restrict__ W2, const float* __restrict__ W,
    const float* __restrict__ b2, const float* __restrict__ Y,
    const float* __restrict__ W1, const float* __restrict__ b1,
    bf16* __restrict__ W2fT, float* __restrict__ b2f, bf16* __restrict__ h)
{
    __shared__ __align__(16) char smem[45056];
    int t = threadIdx.x, bid = blockIdx.x;
    int w = t >> 6, l = t & 63;
    int lm = l & 15, q2 = l >> 4, q8 = q2 * 8;

    if (bid < 2048) {
        int i = bid & 63, pt = bid >> 6;   // i fast: cohort shares W2 row-slab
        bf16* sW = (bf16*)smem;
        bf16* sA = sW + 64 * 72;
        bf16* sT = sA + 128 * 72;
        int p0 = pt * 128;

#pragma unroll
        for (int kk = 0; kk < 16; kk++) {
            int idx = t + 256 * kk;
            sW[(idx >> 6) * 72 + (idx & 63)] = (bf16)W[idx];
        }
        {
            const float* src = W2 + (size_t)p0 * 4096 + i * 64;
#pragma unroll
            for (int kk = 0; kk < 8; kk++) {
                int c = t + 256 * kk;
                int row = c >> 4, j4 = (c & 15) * 4;
                float4 v = *(const float4*)(src + (size_t)row * 4096 + j4);
                bf16 tmp[4] = {(bf16)v.x, (bf16)v.y, (bf16)v.z, (bf16)v.w};
                *(uint2*)(sA + row * 72 + j4) = *(const uint2*)tmp;
            }
        }
        __syncthreads();

        floatx4 acc[2][4] = {};
#pragma unroll
        for (int kc = 0; kc < 2; kc++) {
            bf16x8 a0 = *(const bf16x8*)(sA + (w * 32 + lm) * 72 + kc * 32 + q8);
            bf16x8 a1 = *(const bf16x8*)(sA + (w * 32 + 16 + lm) * 72 + kc * 32 + q8);
#pragma unroll
            for (int jn = 0; jn < 4; jn++) {
                bf16x8 bf_ = *(const bf16x8*)(sW + (jn * 16 + lm) * 72 + kc * 32 + q8);
                acc[0][jn] = MFMA16(a0, bf_, acc[0][jn]);
                acc[1][jn] = MFMA16(a1, bf_, acc[1][jn]);
            }
        }
#pragma unroll
        for (int im = 0; im < 2; im++)
#pragma unroll
            for (int jn = 0; jn < 4; jn++) {
                int pr = w * 32 + im * 16 + q2 * 4;
                int lc = jn * 16 + lm;
                union { bf16 h4[4]; uint2 u; } pk;
#pragma unroll
                for (int r = 0; r < 4; r++) pk.h4[r] = (bf16)acc[im][jn][r];
                *(uint2*)(sT + lc * 136 + pr) = pk.u;
            }
        __syncthreads();
#pragma unroll
        for (int kk = 0; kk < 4; kk++) {
            int c = t + 256 * kk;
            int row = c >> 4, off = (c & 15) * 8;
            uint4 v = *(const uint4*)(sT + row * 136 + off);
            *(uint4*)(W2fT + (size_t)(i * 64 + row) * 4096 + p0 + off) = v;
        }
        return;
    }

    if (bid < 2112) {
        int i = bid - 2048;
        if (t < 64) {
            float acc = 0.f;
            const float* b2r = b2 + i * 64;
            const float* wr_ = W + t * 64;
#pragma unroll
            for (int j = 0; j < 64; j++) acc = fmaf(b2r[j], wr_[j], acc);
            b2f[i * 64 + t] = acc;
        }
        return;
    }

    {
        int q = bid - 2112;
        int m0 = (q >> 5) * 128, n0 = (q & 31) * 128;
        bf16* sY = (bf16*)smem;
        bf16* sWT = sY + 128 * 72;

#pragma unroll
        for (int kk = 0; kk < 8; kk++) {
            int c = t + 256 * kk;
            int row = c >> 4, c4 = (c & 15) * 4;
            float4 v = *(const float4*)(Y + (size_t)(m0 + row) * 64 + c4);
            bf16 tmp[4] = {(bf16)v.x, (bf16)v.y, (bf16)v.z, (bf16)v.w};
            *(uint2*)(sY + row * 72 + c4) = *(const uint2*)tmp;
        }
#pragma unroll
        for (int kk = 0; kk < 8; kk++) {
            int c = t + 256 * kk;
            int k = c >> 5, j4 = (c & 31) * 4;
            float4 v = *(const float4*)(W1 + (size_t)k * 4096 + n0 + j4);
            sWT[(j4 + 0) * 72 + k] = (bf16)v.x;
            sWT[(j4 + 1) * 72 + k] = (bf16)v.y;
            sWT[(j4 + 2) * 72 + k] = (bf16)v.z;
            sWT[(j4 + 3) * 72 + k] = (bf16)v.w;
        }
        __syncthreads();

        int wn = (w & 1) * 64, wm = (w >> 1) * 64;
        floatx4 acc[4][4] = {};
#pragma unroll
        for (int kc = 0; kc < 2; kc++) {
            bf16x8 af[4], bfr[4];
#pragma unroll
            for (int i = 0; i < 4; i++)
                af[i] = *(const bf16x8*)(sWT + (wn + i * 16 + lm) * 72 + kc * 32 + q8);
#pragma unroll
            for (int j = 0; j < 4; j++)
                bfr[j] = *(const bf16x8*)(sY + (wm + j * 16 + lm) * 72 + kc * 32 + q8);
#pragma unroll
            for (int i = 0; i < 4; i++)
#pragma unroll
                for (int j = 0; j < 4; j++)
                    acc[i][j] = MFMA16(af[i], bfr[j], acc[i][j]);
        }
#pragma unroll
        for (int i = 0; i < 4; i++) {
            int nb = n0 + wn + i * 16 + q2 * 4;
            float4 bv = *(const float4*)(b1 + nb);
            float bb[4] = {bv.x, bv.y, bv.z, bv.w};
#pragma unroll
            for (int j = 0; j < 4; j++) {
                int m = m0 + wm + j * 16 + lm;
                union { bf16 h4[4]; uint2 u; } pk;
#pragma unroll
                for (int r = 0; r < 4; r++) {
                    float v = acc[i][j][r] + bb[r];
                    v = v / (1.f + __expf(-v));
                    pk.h4[r] = (bf16)v;
                }
                *(uint2*)(h + (size_t)m * 4096 + nb) = pk.u;
            }
        }
    }
}

// ---------------------------------------------------------------------------
// Kernel 2: C = A @ BT^T + bias, 128x128 tile, BK=32, double-buffered LDS,
// one barrier per K-iter, 16x16x32 MFMA 4x4/wave (R4-proven: 162 us, 848 TF).
// 32x32x16 variant REGRESSED (R6: 182 us, 3x bank conflicts — 32-row frag
// reads alternate between only 2 banks at 64 B row stride). Keep 16x16.
// ---------------------------------------------------------------------------
__global__ __launch_bounds__(256, 4) void gemm_bt_bias(
    const bf16* __restrict__ A, const bf16* __restrict__ BT,
    const float* __restrict__ bias, bf16* __restrict__ C)
{
    __shared__ bf16 sA[2][4096];
    __shared__ bf16 sB[2][4096];
    int t = threadIdx.x, w = t >> 6, l = t & 63;
    int bid = blockIdx.x;
    int xcd = bid & 7, local = bid >> 3;
    int mt = xcd * 4 + (local & 3), nt = local >> 2;
    int m0 = mt * 128, n0 = nt * 128;
    int lm = l & 15, q2 = l >> 4;
    int soff = ((q2 - (l & 3)) & 3) * 8;
    int wr = (w >> 1) * 64, wc = (w & 1) * 64;
    int rowA = (w * 64 + l) >> 2;
    int ko = (((l & 3) + rowA) & 3) * 8;
    const bf16* pa = A + (size_t)(m0 + rowA) * 4096 + ko;
    const bf16* pb = BT + (size_t)(n0 + rowA) * 4096 + ko;
    const int base0 = (w * 64) * 8, base1 = (w * 64 + 256) * 8;

    floatx4 acc[4][4] = {};
    auto issue = [&](int buf, const bf16* a, const bf16* b) {
        gload_lds16(a, &sA[buf][base0]);
        gload_lds16(a + (size_t)64 * 4096, &sA[buf][base1]);
        gload_lds16(b, &sB[buf][base0]);
        gload_lds16(b + (size_t)64 * 4096, &sB[buf][base1]);
    };
    issue(0, pa, pb);
    pa += 32; pb += 32;
    __syncthreads();
    for (int kt = 0; kt < 128; ++kt) {
        int cur = kt & 1;
        if (kt + 1 < 128) { issue(cur ^ 1, pa, pb); pa += 32; pb += 32; }
        const bf16* LA = sA[cur];
        const bf16* LB = sB[cur];
        bf16x8 af[4], bfr[4];
#pragma unroll
        for (int i = 0; i < 4; i++)
            af[i] = *(const bf16x8*)(LA + (wr + i * 16 + lm) * 32 + soff);
#pragma unroll
        for (int j = 0; j < 4; j++)
            bfr[j] = *(const bf16x8*)(LB + (wc + j * 16 + lm) * 32 + soff);
#pragma unroll
        for (int i = 0; i < 4; i++)
#pragma unroll
            for (int j = 0; j < 4; j++)
                acc[i][j] = MFMA16(af[i], bfr[j], acc[i][j]);
        __syncthreads();
    }
#pragma unroll
    for (int i = 0; i < 4; i++) {
        int r0 = m0 + wr + i * 16 + q2 * 4;
#pragma unroll
        for (int j = 0; j < 4; j++) {
            int cc = n0 + wc + j * 16 + lm;
            float bb = bias[cc];
#pragma unroll
            for (int r = 0; r < 4; r++)
                C[(size_t)(r0 + r) * 4096 + cc] = (bf16)(acc[i][j][r] + bb);
        }
    }
}

// ---------------------------------------------------------------------------
// Kernel 3: out = F X F^T (X symmetric; F = reshape(h W2f + b2f)).
// (R4-proven, unchanged)
// ---------------------------------------------------------------------------
__global__ __launch_bounds__(256) void batched_congruence(
    const float* __restrict__ x, const bf16* __restrict__ F,
    float* __restrict__ out)
{
    __shared__ bf16 sX[64 * ST], sF[64 * ST], sT[64 * ST];
    int t = threadIdx.x, w = t >> 6, l = t & 63;
    int b = blockIdx.x;
    int lm = l & 15, q2 = l >> 4, q8 = q2 * 8;
    int r0 = (w >> 1) * 32, c0 = (w & 1) * 32;

    const float4* xb = (const float4*)(x + (size_t)b * 2304);
    float4 v0 = xb[t];
    float4 v1 = xb[t + 256];
    float4 v2 = (t < 64) ? xb[t + 512] : make_float4(0.f, 0.f, 0.f, 0.f);
    {
        const uint4* gf = (const uint4*)(F + (size_t)b * 4096);
#pragma unroll
        for (int kk = 0; kk < 2; kk++) {
            int c = t + 256 * kk;
            *(uint4*)(sF + (c >> 3) * ST + (c & 7) * 8) = gf[c];
        }
    }
    {
        unsigned* sx32 = (unsigned*)sX;
#pragma unroll
        for (int kk = 0; kk < 4; kk++) {
            int idx = t + 256 * kk;
            if (idx < 384) {
                int r = idx >> 3, d = 24 + (idx & 7);
                sx32[r * 36 + d] = 0u;
            } else if (idx < 896) {
                int k2 = idx - 384;
                int r = 48 + (k2 >> 5), d = k2 & 31;
                unsigned val = 0u;
                if (d == (r >> 1)) val = (r & 1) ? 0x3F800000u : 0x00003F80u;
                sx32[r * 36 + d] = val;
            }
        }
    }
    {
        int c = t;
        bf16 p4[4];
        p4[0] = (bf16)v0.x; p4[1] = (bf16)v0.y; p4[2] = (bf16)v0.z; p4[3] = (bf16)v0.w;
        *(uint2*)(sX + (c / 12) * ST + (c % 12) * 4) = *(const uint2*)p4;
        c = t + 256;
        p4[0] = (bf16)v1.x; p4[1] = (bf16)v1.y; p4[2] = (bf16)v1.z; p4[3] = (bf16)v1.w;
        *(uint2*)(sX + (c / 12) * ST + (c % 12) * 4) = *(const uint2*)p4;
        if (t < 64) {
            c = t + 512;
            p4[0] = (bf16)v2.x; p4[1] = (bf16)v2.y; p4[2] = (bf16)v2.z; p4[3] = (bf16)v2.w;
            *(uint2*)(sX + (c / 12) * ST + (c % 12) * 4) = *(const uint2*)p4;
        }
    }
    __syncthreads();

    auto mm = [&](const bf16* PA, const bf16* PB, floatx4 acc[2][2]) {
#pragma unroll
        for (int kc = 0; kc < 2; kc++) {
            bf16x8 a0 = *(const bf16x8*)(PA + (r0 + lm) * ST + kc * 32 + q8);
            bf16x8 a1 = *(const bf16x8*)(PA + (r0 + 16 + lm) * ST + kc * 32 + q8);
            bf16x8 b0 = *(const bf16x8*)(PB + (c0 + lm) * ST + kc * 32 + q8);
            bf16x8 b1 = *(const bf16x8*)(PB + (c0 + 16 + lm) * ST + kc * 32 + q8);
            acc[0][0] = MFMA16(a0, b0, acc[0][0]);
            acc[0][1] = MFMA16(a0, b1, acc[0][1]);
            acc[1][0] = MFMA16(a1, b0, acc[1][0]);
            acc[1][1] = MFMA16(a1, b1, acc[1][1]);
        }
    };

    floatx4 z = {0.f, 0.f, 0.f, 0.f};
    {   // S2: Q = X . F^T = T^T; transposed store -> sT = T row-major
        floatx4 a2[2][2] = {{z, z}, {z, z}};
        mm(sX, sF, a2);
#pragma unroll
        for (int i = 0; i < 2; i++)
#pragma unroll
            for (int j = 0; j < 2; j++) {
                int R = r0 + i * 16 + q2 * 4;
                int Cc = c0 + j * 16 + lm;
                union { bf16 h4[4]; uint2 u; } pk;
#pragma unroll
                for (int r = 0; r < 4; r++) pk.h4[r] = (bf16)a2[i][j][r];
                *(uint2*)(sT + Cc * ST + R) = pk.u;
            }
    }
    __syncthreads();
    {   // S3: out = T . F^T; out symmetric -> float4 store at (Cc, R..R+3)
        floatx4 a3[2][2] = {{z, z}, {z, z}};
        mm(sT, sF, a3);
        float* ob = out + (size_t)b * 4096;
#pragma unroll
        for (int i = 0; i < 2; i++)
#pragma unroll
            for (int j = 0; j < 2; j++) {
                int R = r0 + i * 16 + q2 * 4;
                int Cc = c0 + j * 16 + lm;
                float4 vout = make_float4(a3[i][j][0], a3[i][j][1], a3[i][j][2], a3[i][j][3]);
                *(float4*)(ob + Cc * 64 + R) = vout;
            }
    }
}

// ---------------------------------------------------------------------------
extern "C" void kernel_launch(void* const* d_in, const int* in_sizes, int n_in,
                              void* d_out, int out_size, void* d_ws, size_t ws_size,
                              hipStream_t stream) {
    const float* x  = (const float*)d_in[0];
    const float* Y  = (const float*)d_in[2];
    const float* W  = (const float*)d_in[3];
    const float* W1 = (const float*)d_in[4];
    const float* b1 = (const float*)d_in[5];
    const float* W2 = (const float*)d_in[6];
    const float* b2 = (const float*)d_in[7];
    float* out = (float*)d_out;

    const size_t NN = (size_t)4096 * 4096;
    bf16* h    = (bf16*)d_ws;
    bf16* W2fT = h + NN;
    bf16* emb  = W2fT + NN;
    float* b2f = (float*)d_out;  // stashed in d_out; read by GEMM, overwritten by cong

    prep_fused<<<3136, 256, 0, stream>>>(W2, W, b2, Y, W1, b1, W2fT, b2f, h);
    gemm_bt_bias<<<1024, 256, 0, stream>>>(h, W2fT, b2f, emb);
    batched_congruence<<<4096, 256, 0, stream>>>(x, emb, out);
}